// Round 3
// baseline (784.914 us; speedup 1.0000x reference)
//
#include <hip/hip_runtime.h>
#include <stdint.h>

#define B_TOK 32768
#define IN    128
#define HID   128
#define NE    32
#define NC    128

typedef __attribute__((ext_vector_type(8))) __bf16 bf16x8;
typedef __attribute__((ext_vector_type(4))) float  f32x4;

static __device__ __forceinline__ unsigned short f2bf(float f) {
    union { float f; uint32_t u; } v; v.f = f;
    uint32_t u = v.u;
    return (unsigned short)((u + 0x7FFFu + ((u >> 16) & 1u)) >> 16);
}

// ---- prep: x fp32 -> bf16 --------------------------------------------------
__global__ void k_convert_x(const float* __restrict__ x, unsigned short* __restrict__ xb) {
    int i = (blockIdx.x * 256 + threadIdx.x) * 4;
    float4 v = *(const float4*)(x + i);
    ushort4 o;
    o.x = f2bf(v.x); o.y = f2bf(v.y); o.z = f2bf(v.z); o.w = f2bf(v.w);
    *(ushort4*)(xb + i) = o;
}

// ---- prep: W1T[e][h][i] = bf16(W1[e][i][h]) --------------------------------
__global__ void k_prep_w1t(const float* __restrict__ W1, unsigned short* __restrict__ W1T) {
    int idx = blockIdx.x * 256 + threadIdx.x;   // e*16384 + h*128 + i
    int i = idx & 127;
    int h = (idx >> 7) & 127;
    int e = idx >> 14;
    W1T[idx] = f2bf(W1[(e * 128 + i) * 128 + h]);
}

// ---- prep: W2cT[e][c][h] = bf16(sum_t W2[e][h][t]*Wc[t][c]); bc2 fold ------
__global__ void k_prep_w2c(const float* __restrict__ W2, const float* __restrict__ Wc,
                           const float* __restrict__ b2, const float* __restrict__ bc,
                           unsigned short* __restrict__ W2cT, float* __restrict__ bc2) {
    __shared__ float row[128];
    int e = blockIdx.x >> 7, h = blockIdx.x & 127;   // grid 32*128
    int c = threadIdx.x;                              // 128 threads
    row[c] = W2[(e * 128 + h) * 128 + c];
    __syncthreads();
    float acc = 0.f;
    #pragma unroll 8
    for (int t = 0; t < 128; ++t) acc += row[t] * Wc[t * 128 + c];   // row[t] broadcast, Wc coalesced
    W2cT[(e * 128 + c) * 128 + h] = f2bf(acc);
    if (h == 0) {
        float a2 = bc[c];
        for (int t = 0; t < 128; ++t) a2 += b2[e * 128 + t] * Wc[t * 128 + c];
        bc2[e * 128 + c] = a2;
    }
}

// ---- router: scores = softmax(relu(x @ Wg + bg), axis=1) -------------------
__global__ __launch_bounds__(256) void k_router(const float* __restrict__ x,
        const float* __restrict__ Wg, const float* __restrict__ bg,
        float* __restrict__ scores) {
    __shared__ float Wgs[128 * 32];
    __shared__ float xs[8][128];
    int tid = threadIdx.x;
    for (int j = tid; j < 4096; j += 256) Wgs[j] = Wg[j];
    int rb = blockIdx.x * 8;
    for (int j = tid; j < 8 * 128; j += 256)
        xs[j >> 7][j & 127] = x[(rb + (j >> 7)) * 128 + (j & 127)];
    __syncthreads();
    int r = tid >> 5;        // 0..7 row in tile
    int e = tid & 31;        // expert
    float acc = bg[e];
    #pragma unroll 8
    for (int i = 0; i < 128; ++i) acc += xs[r][i] * Wgs[i * 32 + e];
    acc = fmaxf(acc, 0.f);
    float m = acc;
    for (int off = 16; off > 0; off >>= 1) m = fmaxf(m, __shfl_xor(m, off, 32));
    float p = __expf(acc - m);
    float s = p;
    for (int off = 16; off > 0; off >>= 1) s += __shfl_xor(s, off, 32);
    scores[(size_t)(rb + r) * 32 + e] = p / s;
}

// ---- main fused: out[:,e,:] = relu(X@W1[e]+b1[e]) @ W2c[e] + bc2[e] --------
// v4: latency-bound fix (round-2 post-mortem: coalesced stores gained only
// ~60us; the real stall is per-wave serial load waits + store drains with
// ~1.7 waves/SIMD and vmcnt's in-order retire forcing drain at each block
// boundary).
//  - 1-wave blocks (64 thr), each looping over 4 experts: X frags loaded
//    once into regs for 4 experts; __syncthreads degenerates to waitcnt
//    (no s_barrier coupling); per-wave fixed costs amortized 4x.
//  - double-buffered weight frags + ISSUE-BEFORE-STORE pipeline: the next
//    phase's first loads (next nt / next half / next expert's W1 nt0) are
//    issued BEFORE each 16-store batch -> their completion needs only
//    vmcnt(16), never a store drain (vmcnt retires in issue order).
//  - H tile XOR-swizzled (byte ^= (row&7)<<4) instead of pad-136: LDS
//    16KB/block, occupancy VGPR-capped (~8 waves/CU) not LDS-capped.
//  - coalesced f32-stage epilogue kept (full 128B lines, nontemporal).
__global__ __launch_bounds__(64, 2) void k_moe(const unsigned short* __restrict__ Xb,
        const unsigned short* __restrict__ W1T, const float* __restrict__ b1,
        const unsigned short* __restrict__ W2cT, const float* __restrict__ bc2,
        float* __restrict__ out) {
    __shared__ __align__(16) unsigned short Hs[64 * 128];   // 16 KB, wave-private
    const int lane = threadIdx.x;
    const int l15  = lane & 15;
    const int quad = lane >> 4;
    const int row0 = blockIdx.x * 64;
    const int e0   = blockIdx.y * 4;
    const int rsel = lane >> 5;              // epilogue: which of 2 rows
    const int cw   = (lane & 31) * 4;        // 32 lanes * 16B = full 512B row

    // ---- persistent X fragments: 64 rows, live across all 4 experts
    bf16x8 xb[4][4];
    #pragma unroll
    for (int bt = 0; bt < 4; ++bt) {
        const unsigned short* xp = Xb + (size_t)(row0 + bt * 16 + l15) * 128 + quad * 8;
        #pragma unroll
        for (int kc = 0; kc < 4; ++kc) xb[bt][kc] = *(const bf16x8*)(xp + kc * 32);
    }

    bf16x8 w1f[2][4], w2f[2][4];
    {   // prologue: preload e0's GEMM1 nt=0 fragments
        const unsigned short* bp = W1T + (size_t)e0 * 16384 + l15 * 128 + quad * 8;
        #pragma unroll
        for (int kc = 0; kc < 4; ++kc) w1f[0][kc] = *(const bf16x8*)(bp + kc * 32);
    }

    #pragma unroll 1
    for (int ei = 0; ei < 4; ++ei) {
        const int e = e0 + ei;
        const unsigned short* w1p = W1T  + (size_t)e * 16384 + l15 * 128 + quad * 8;
        const unsigned short* w2p = W2cT + (size_t)e * 16384 + l15 * 128 + quad * 8;
        const float* b1p = b1  + e * 128 + quad * 4;
        const float* bcp = bc2 + e * 128 + quad * 4;
        const unsigned short* w1n = W1T + (size_t)(ei < 3 ? e + 1 : e) * 16384
                                        + l15 * 128 + quad * 8;   // next-e prefetch (clamped)

        // ---- GEMM1: lane holds h = nt*16+quad*4+r, b = bt*16+l15
        #pragma unroll
        for (int nt = 0; nt < 8; ++nt) {
            const int cur = nt & 1, nxt = cur ^ 1;
            if (nt < 7) {                       // prefetch next nt
                const unsigned short* bp = w1p + (nt + 1) * 16 * 128;
                #pragma unroll
                for (int kc = 0; kc < 4; ++kc) w1f[nxt][kc] = *(const bf16x8*)(bp + kc * 32);
            } else {                            // prefetch GEMM2 half0 nt=0
                #pragma unroll
                for (int kc = 0; kc < 4; ++kc) w2f[0][kc] = *(const bf16x8*)(w2p + kc * 32);
            }
            float4 bias = *(const float4*)(b1p + nt * 16);
            f32x4 acc[4];
            #pragma unroll
            for (int bt = 0; bt < 4; ++bt) acc[bt] = (f32x4){bias.x, bias.y, bias.z, bias.w};
            #pragma unroll
            for (int kc = 0; kc < 4; ++kc) {
                #pragma unroll
                for (int bt = 0; bt < 4; ++bt)
                    acc[bt] = __builtin_amdgcn_mfma_f32_16x16x32_bf16(w1f[cur][kc], xb[bt][kc], acc[bt], 0, 0, 0);
            }
            // relu + cvt + packed 8B LDS write, XOR-swizzled (2-way max)
            #pragma unroll
            for (int bt = 0; bt < 4; ++bt) {
                ushort4 hq;
                hq.x = f2bf(fmaxf(acc[bt][0], 0.f));
                hq.y = f2bf(fmaxf(acc[bt][1], 0.f));
                hq.z = f2bf(fmaxf(acc[bt][2], 0.f));
                hq.w = f2bf(fmaxf(acc[bt][3], 0.f));
                int row = bt * 16 + l15;
                int col = (nt * 16 + quad * 4) ^ ((row & 7) << 3);   // ushort units
                *(ushort4*)(Hs + row * 128 + col) = hq;
            }
        }
        __syncthreads();   // 1-wave block: compiles to lgkmcnt fence

        // ---- H B-fragments (regs for all of GEMM2)
        bf16x8 hb[4][4];
        #pragma unroll
        for (int bt = 0; bt < 4; ++bt) {
            int row = bt * 16 + l15;
            #pragma unroll
            for (int kc = 0; kc < 4; ++kc) {
                int col = (kc * 32 + quad * 8) ^ ((row & 7) << 3);
                hb[bt][kc] = *(const bf16x8*)(Hs + row * 128 + col);
            }
        }
        __syncthreads();

        float* stage = (float*)Hs;   // reuse as [32][128] f32 stage, XOR-swizzled

        // ---- GEMM2 in two 32-row halves; coalesced epilogue per half
        #pragma unroll
        for (int half = 0; half < 2; ++half) {
            #pragma unroll
            for (int nt = 0; nt < 8; ++nt) {
                const int cur = nt & 1, nxt = cur ^ 1;
                if (nt < 7) {                   // prefetch next nt
                    const unsigned short* bp = w2p + (nt + 1) * 16 * 128;
                    #pragma unroll
                    for (int kc = 0; kc < 4; ++kc) w2f[nxt][kc] = *(const bf16x8*)(bp + kc * 32);
                } else if (half == 0) {         // prefetch half1 nt=0 (before half0 stores!)
                    #pragma unroll
                    for (int kc = 0; kc < 4; ++kc) w2f[nxt][kc] = *(const bf16x8*)(w2p + kc * 32);
                } else {                        // prefetch next-e GEMM1 nt=0 (before half1 stores!)
                    #pragma unroll
                    for (int kc = 0; kc < 4; ++kc) w1f[0][kc] = *(const bf16x8*)(w1n + kc * 32);
                }
                float4 bias = *(const float4*)(bcp + nt * 16);
                f32x4 acc2[2];
                acc2[0] = (f32x4){bias.x, bias.y, bias.z, bias.w};
                acc2[1] = acc2[0];
                #pragma unroll
                for (int kc = 0; kc < 4; ++kc) {
                    #pragma unroll
                    for (int btl = 0; btl < 2; ++btl)
                        acc2[btl] = __builtin_amdgcn_mfma_f32_16x16x32_bf16(
                            w2f[cur][kc], hb[half * 2 + btl][kc], acc2[btl], 0, 0, 0);
                }
                #pragma unroll
                for (int btl = 0; btl < 2; ++btl) {
                    int row = btl * 16 + l15;                          // 0..31 within half
                    int col = (nt * 16 + quad * 4) ^ ((row & 7) << 2); // f32 units
                    *(f32x4*)(stage + row * 128 + col) = acc2[btl];
                }
            }
            __syncthreads();
            // readback: each instr stores 2 complete 512B rows (8 full 128B lines)
            #pragma unroll
            for (int j = 0; j < 16; ++j) {
                int row = j * 2 + rsel;
                int col = cw ^ ((row & 7) << 2);
                f32x4 v = *(const f32x4*)(stage + row * 128 + col);
                float* p = out + (size_t)(row0 + half * 32 + row) * (NE * NC) + e * NC + cw;
                __builtin_nontemporal_store(v, (f32x4*)p);
            }
            __syncthreads();   // stage WAR fence before next half / next e
        }
    }
}

extern "C" void kernel_launch(void* const* d_in, const int* in_sizes, int n_in,
                              void* d_out, int out_size, void* d_ws, size_t ws_size,
                              hipStream_t stream) {
    const float* x  = (const float*)d_in[0];
    const float* Wg = (const float*)d_in[1];
    const float* bg = (const float*)d_in[2];
    const float* W1 = (const float*)d_in[3];
    const float* b1 = (const float*)d_in[4];
    const float* W2 = (const float*)d_in[5];
    const float* b2 = (const float*)d_in[6];
    const float* Wc = (const float*)d_in[7];
    const float* bc = (const float*)d_in[8];

    float* out    = (float*)d_out;
    float* scores = out + (size_t)B_TOK * NE * NC;

    unsigned short* Xb   = (unsigned short*)d_ws;            // 32768*128 bf16 = 8 MB
    unsigned short* W1T  = Xb + (size_t)B_TOK * IN;          // 32*128*128 bf16 = 1 MB
    unsigned short* W2cT = W1T + NE * IN * HID;              // 32*128*128 bf16 = 1 MB
    float*          bc2  = (float*)(W2cT + NE * HID * NC);   // 32*128 f32 = 16 KB

    hipLaunchKernelGGL(k_convert_x, dim3((B_TOK * IN) / (256 * 4)), dim3(256), 0, stream, x, Xb);
    hipLaunchKernelGGL(k_prep_w1t,  dim3((NE * IN * HID) / 256),    dim3(256), 0, stream, W1, W1T);
    hipLaunchKernelGGL(k_prep_w2c,  dim3(NE * HID),                 dim3(128), 0, stream,
                       W2, Wc, b2, bc, W2cT, bc2);
    hipLaunchKernelGGL(k_router,    dim3(B_TOK / 8),                dim3(256), 0, stream,
                       x, Wg, bg, scores);
    // grid: x = row-blocks of 64 (fastest) -> XCD = x%8: per-XCD X slice 1MB
    // + all experts' weights 2MB resident in each 4MB L2. y = expert groups of 4.
    hipLaunchKernelGGL(k_moe,       dim3(B_TOK / 64, NE / 4),       dim3(64), 0, stream,
                       Xb, W1T, b1, W2cT, bc2, out);
}

// Round 4
// 747.568 us; speedup vs baseline: 1.0500x; 1.0500x over previous
//
#include <hip/hip_runtime.h>
#include <stdint.h>

#define B_TOK 32768
#define IN    128
#define HID   128
#define NE    32
#define NC    128

typedef __attribute__((ext_vector_type(8))) __bf16 bf16x8;
typedef __attribute__((ext_vector_type(4))) float  f32x4;

// wave-private LDS fence: orders ds ops (RAW/WAR) WITHOUT draining vmcnt —
// __syncthreads would emit s_waitcnt vmcnt(0) and stall the nt-store queue.
#define LDS_FENCE() asm volatile("s_waitcnt lgkmcnt(0)" ::: "memory")

static __device__ __forceinline__ unsigned short f2bf(float f) {
    union { float f; uint32_t u; } v; v.f = f;
    uint32_t u = v.u;
    return (unsigned short)((u + 0x7FFFu + ((u >> 16) & 1u)) >> 16);
}

// ---- prep: x fp32 -> bf16 --------------------------------------------------
__global__ void k_convert_x(const float* __restrict__ x, unsigned short* __restrict__ xb) {
    int i = (blockIdx.x * 256 + threadIdx.x) * 4;
    float4 v = *(const float4*)(x + i);
    ushort4 o;
    o.x = f2bf(v.x); o.y = f2bf(v.y); o.z = f2bf(v.z); o.w = f2bf(v.w);
    *(ushort4*)(xb + i) = o;
}

// ---- prep: W1T[e][h][i] = bf16(W1[e][i][h]) --------------------------------
__global__ void k_prep_w1t(const float* __restrict__ W1, unsigned short* __restrict__ W1T) {
    int idx = blockIdx.x * 256 + threadIdx.x;   // e*16384 + h*128 + i
    int i = idx & 127;
    int h = (idx >> 7) & 127;
    int e = idx >> 14;
    W1T[idx] = f2bf(W1[(e * 128 + i) * 128 + h]);
}

// ---- prep: W2cT[e][c][h] = bf16(sum_t W2[e][h][t]*Wc[t][c]); bc2 fold ------
__global__ void k_prep_w2c(const float* __restrict__ W2, const float* __restrict__ Wc,
                           const float* __restrict__ b2, const float* __restrict__ bc,
                           unsigned short* __restrict__ W2cT, float* __restrict__ bc2) {
    __shared__ float row[128];
    int e = blockIdx.x >> 7, h = blockIdx.x & 127;   // grid 32*128
    int c = threadIdx.x;                              // 128 threads
    row[c] = W2[(e * 128 + h) * 128 + c];
    __syncthreads();
    float acc = 0.f;
    #pragma unroll 8
    for (int t = 0; t < 128; ++t) acc += row[t] * Wc[t * 128 + c];   // row[t] broadcast, Wc coalesced
    W2cT[(e * 128 + c) * 128 + h] = f2bf(acc);
    if (h == 0) {
        float a2 = bc[c];
        for (int t = 0; t < 128; ++t) a2 += b2[e * 128 + t] * Wc[t * 128 + c];
        bc2[e * 128 + c] = a2;
    }
}

// ---- router: scores = softmax(relu(x @ Wg + bg), axis=1) -------------------
__global__ __launch_bounds__(256) void k_router(const float* __restrict__ x,
        const float* __restrict__ Wg, const float* __restrict__ bg,
        float* __restrict__ scores) {
    __shared__ float Wgs[128 * 32];
    __shared__ float xs[8][128];
    int tid = threadIdx.x;
    for (int j = tid; j < 4096; j += 256) Wgs[j] = Wg[j];
    int rb = blockIdx.x * 8;
    for (int j = tid; j < 8 * 128; j += 256)
        xs[j >> 7][j & 127] = x[(rb + (j >> 7)) * 128 + (j & 127)];
    __syncthreads();
    int r = tid >> 5;        // 0..7 row in tile
    int e = tid & 31;        // expert
    float acc = bg[e];
    #pragma unroll 8
    for (int i = 0; i < 128; ++i) acc += xs[r][i] * Wgs[i * 32 + e];
    acc = fmaxf(acc, 0.f);
    float m = acc;
    for (int off = 16; off > 0; off >>= 1) m = fmaxf(m, __shfl_xor(m, off, 32));
    float p = __expf(acc - m);
    float s = p;
    for (int off = 16; off > 0; off >>= 1) s += __shfl_xor(s, off, 32);
    scores[(size_t)(rb + r) * 32 + e] = p / s;
}

// ---- main fused: out[:,e,:] = relu(X@W1[e]+b1[e]) @ W2c[e] + bc2[e] --------
// v5 = v4's pipeline with ZERO barriers (round-3 post-mortem: v4's
// __syncthreads each drained vmcnt(0), serializing the nt-store queue and
// defeating the issue-before-store prefetch; that was the regression).
// Wave-private LDS needs only lgkmcnt ordering -> inline-asm LDS_FENCE.
//  - 1-wave blocks (64 thr) looping over 4 experts: X frags in regs x4 reuse.
//  - double-buffered weight frags; next phase's loads issued BEFORE each
//    16-store batch: with in-order vmcnt retire they complete at vmcnt(16),
//    stores drain in background (never vmcnt(0) on the critical path).
//  - H tile XOR-swizzled 16KB; f32 stage reuses it; coalesced nt stores.
__global__ __launch_bounds__(64, 2) void k_moe(const unsigned short* __restrict__ Xb,
        const unsigned short* __restrict__ W1T, const float* __restrict__ b1,
        const unsigned short* __restrict__ W2cT, const float* __restrict__ bc2,
        float* __restrict__ out) {
    __shared__ __align__(16) unsigned short Hs[64 * 128];   // 16 KB, wave-private
    const int lane = threadIdx.x;
    const int l15  = lane & 15;
    const int quad = lane >> 4;
    const int row0 = blockIdx.x * 64;
    const int e0   = blockIdx.y * 4;
    const int rsel = lane >> 5;              // epilogue: which of 2 rows
    const int cw   = (lane & 31) * 4;        // 32 lanes * 16B = full 512B row

    // ---- persistent X fragments: 64 rows, live across all 4 experts
    bf16x8 xb[4][4];
    #pragma unroll
    for (int bt = 0; bt < 4; ++bt) {
        const unsigned short* xp = Xb + (size_t)(row0 + bt * 16 + l15) * 128 + quad * 8;
        #pragma unroll
        for (int kc = 0; kc < 4; ++kc) xb[bt][kc] = *(const bf16x8*)(xp + kc * 32);
    }

    bf16x8 w1f[2][4], w2f[2][4];
    {   // prologue: preload e0's GEMM1 nt=0 fragments
        const unsigned short* bp = W1T + (size_t)e0 * 16384 + l15 * 128 + quad * 8;
        #pragma unroll
        for (int kc = 0; kc < 4; ++kc) w1f[0][kc] = *(const bf16x8*)(bp + kc * 32);
    }

    #pragma unroll 1
    for (int ei = 0; ei < 4; ++ei) {
        const int e = e0 + ei;
        const unsigned short* w1p = W1T  + (size_t)e * 16384 + l15 * 128 + quad * 8;
        const unsigned short* w2p = W2cT + (size_t)e * 16384 + l15 * 128 + quad * 8;
        const float* b1p = b1  + e * 128 + quad * 4;
        const float* bcp = bc2 + e * 128 + quad * 4;
        const unsigned short* w1n = W1T + (size_t)(ei < 3 ? e + 1 : e) * 16384
                                        + l15 * 128 + quad * 8;   // next-e prefetch (clamped)

        // ---- GEMM1: lane holds h = nt*16+quad*4+r, b = bt*16+l15
        #pragma unroll
        for (int nt = 0; nt < 8; ++nt) {
            const int cur = nt & 1, nxt = cur ^ 1;
            if (nt < 7) {                       // prefetch next nt
                const unsigned short* bp = w1p + (nt + 1) * 16 * 128;
                #pragma unroll
                for (int kc = 0; kc < 4; ++kc) w1f[nxt][kc] = *(const bf16x8*)(bp + kc * 32);
            } else {                            // prefetch GEMM2 half0 nt=0
                #pragma unroll
                for (int kc = 0; kc < 4; ++kc) w2f[0][kc] = *(const bf16x8*)(w2p + kc * 32);
            }
            float4 bias = *(const float4*)(b1p + nt * 16);
            f32x4 acc[4];
            #pragma unroll
            for (int bt = 0; bt < 4; ++bt) acc[bt] = (f32x4){bias.x, bias.y, bias.z, bias.w};
            #pragma unroll
            for (int kc = 0; kc < 4; ++kc) {
                #pragma unroll
                for (int bt = 0; bt < 4; ++bt)
                    acc[bt] = __builtin_amdgcn_mfma_f32_16x16x32_bf16(w1f[cur][kc], xb[bt][kc], acc[bt], 0, 0, 0);
            }
            // relu + cvt + packed 8B LDS write, XOR-swizzled (2-way max)
            #pragma unroll
            for (int bt = 0; bt < 4; ++bt) {
                ushort4 hq;
                hq.x = f2bf(fmaxf(acc[bt][0], 0.f));
                hq.y = f2bf(fmaxf(acc[bt][1], 0.f));
                hq.z = f2bf(fmaxf(acc[bt][2], 0.f));
                hq.w = f2bf(fmaxf(acc[bt][3], 0.f));
                int row = bt * 16 + l15;
                int col = (nt * 16 + quad * 4) ^ ((row & 7) << 3);   // ushort units
                *(ushort4*)(Hs + row * 128 + col) = hq;
            }
        }
        LDS_FENCE();   // H writes -> hb reads (RAW), lgkm only

        // ---- H B-fragments (regs for all of GEMM2)
        bf16x8 hb[4][4];
        #pragma unroll
        for (int bt = 0; bt < 4; ++bt) {
            int row = bt * 16 + l15;
            #pragma unroll
            for (int kc = 0; kc < 4; ++kc) {
                int col = (kc * 32 + quad * 8) ^ ((row & 7) << 3);
                hb[bt][kc] = *(const bf16x8*)(Hs + row * 128 + col);
            }
        }
        LDS_FENCE();   // hb reads -> stage overwrite (WAR), lgkm only

        float* stage = (float*)Hs;   // reuse as [32][128] f32 stage, XOR-swizzled

        // ---- GEMM2 in two 32-row halves; coalesced epilogue per half
        #pragma unroll
        for (int half = 0; half < 2; ++half) {
            #pragma unroll
            for (int nt = 0; nt < 8; ++nt) {
                const int cur = nt & 1, nxt = cur ^ 1;
                if (nt < 7) {                   // prefetch next nt
                    const unsigned short* bp = w2p + (nt + 1) * 16 * 128;
                    #pragma unroll
                    for (int kc = 0; kc < 4; ++kc) w2f[nxt][kc] = *(const bf16x8*)(bp + kc * 32);
                } else if (half == 0) {         // prefetch half1 nt=0 (before half0 stores!)
                    #pragma unroll
                    for (int kc = 0; kc < 4; ++kc) w2f[nxt][kc] = *(const bf16x8*)(w2p + kc * 32);
                } else {                        // prefetch next-e GEMM1 nt=0 (before half1 stores!)
                    #pragma unroll
                    for (int kc = 0; kc < 4; ++kc) w1f[0][kc] = *(const bf16x8*)(w1n + kc * 32);
                }
                float4 bias = *(const float4*)(bcp + nt * 16);
                f32x4 acc2[2];
                acc2[0] = (f32x4){bias.x, bias.y, bias.z, bias.w};
                acc2[1] = acc2[0];
                #pragma unroll
                for (int kc = 0; kc < 4; ++kc) {
                    #pragma unroll
                    for (int btl = 0; btl < 2; ++btl)
                        acc2[btl] = __builtin_amdgcn_mfma_f32_16x16x32_bf16(
                            w2f[cur][kc], hb[half * 2 + btl][kc], acc2[btl], 0, 0, 0);
                }
                #pragma unroll
                for (int btl = 0; btl < 2; ++btl) {
                    int row = btl * 16 + l15;                          // 0..31 within half
                    int col = (nt * 16 + quad * 4) ^ ((row & 7) << 2); // f32 units
                    *(f32x4*)(stage + row * 128 + col) = acc2[btl];
                }
            }
            LDS_FENCE();   // stage writes -> readback (RAW), lgkm only
            // readback: each instr stores 2 complete 512B rows (8 full 128B lines)
            #pragma unroll
            for (int j = 0; j < 16; ++j) {
                int row = j * 2 + rsel;
                int col = cw ^ ((row & 7) << 2);
                f32x4 v = *(const f32x4*)(stage + row * 128 + col);
                float* p = out + (size_t)(row0 + half * 32 + row) * (NE * NC) + e * NC + cw;
                __builtin_nontemporal_store(v, (f32x4*)p);
            }
            LDS_FENCE();   // readback -> next stage writes (WAR), lgkm only
        }
    }
}

extern "C" void kernel_launch(void* const* d_in, const int* in_sizes, int n_in,
                              void* d_out, int out_size, void* d_ws, size_t ws_size,
                              hipStream_t stream) {
    const float* x  = (const float*)d_in[0];
    const float* Wg = (const float*)d_in[1];
    const float* bg = (const float*)d_in[2];
    const float* W1 = (const float*)d_in[3];
    const float* b1 = (const float*)d_in[4];
    const float* W2 = (const float*)d_in[5];
    const float* b2 = (const float*)d_in[6];
    const float* Wc = (const float*)d_in[7];
    const float* bc = (const float*)d_in[8];

    float* out    = (float*)d_out;
    float* scores = out + (size_t)B_TOK * NE * NC;

    unsigned short* Xb   = (unsigned short*)d_ws;            // 32768*128 bf16 = 8 MB
    unsigned short* W1T  = Xb + (size_t)B_TOK * IN;          // 32*128*128 bf16 = 1 MB
    unsigned short* W2cT = W1T + NE * IN * HID;              // 32*128*128 bf16 = 1 MB
    float*          bc2  = (float*)(W2cT + NE * HID * NC);   // 32*128 f32 = 16 KB

    hipLaunchKernelGGL(k_convert_x, dim3((B_TOK * IN) / (256 * 4)), dim3(256), 0, stream, x, Xb);
    hipLaunchKernelGGL(k_prep_w1t,  dim3((NE * IN * HID) / 256),    dim3(256), 0, stream, W1, W1T);
    hipLaunchKernelGGL(k_prep_w2c,  dim3(NE * HID),                 dim3(128), 0, stream,
                       W2, Wc, b2, bc, W2cT, bc2);
    hipLaunchKernelGGL(k_router,    dim3(B_TOK / 8),                dim3(256), 0, stream,
                       x, Wg, bg, scores);
    // grid: x = row-blocks of 64 (fastest) -> XCD = x%8: per-XCD X slice 1MB
    // + all experts' weights 2MB resident in each 4MB L2. y = expert groups of 4.
    hipLaunchKernelGGL(k_moe,       dim3(B_TOK / 64, NE / 4),       dim3(64), 0, stream,
                       Xb, W1T, b1, W2cT, bc2, out);
}